// Round 4
// baseline (1200.261 us; speedup 1.0000x reference)
//
#include <hip/hip_runtime.h>

typedef unsigned int uint32;
typedef unsigned short ushort16;

typedef __attribute__((ext_vector_type(8))) short bf16x8;
typedef __attribute__((ext_vector_type(4))) float f32x4;

#define NNODES 32768
#define DFEAT 384
#define KPAD1 320

__device__ __forceinline__ float bf2f(ushort16 u) {
  union { uint32 i; float f; } x; x.i = ((uint32)u) << 16; return x.f;
}
__device__ __forceinline__ float bflo(uint32 v) {
  union { uint32 i; float f; } x; x.i = v << 16; return x.f;
}
__device__ __forceinline__ float bfhi(uint32 v) {
  union { uint32 i; float f; } x; x.i = v & 0xffff0000u; return x.f;
}
__device__ __forceinline__ ushort16 f2bf(float f) {
  union { float f; uint32 i; } x; x.f = f;
  uint32 r = (x.i + 0x7fffu + ((x.i >> 16) & 1u)) >> 16;
  return (ushort16)r;
}

// ---------------- x_nodes f32 [32768,300] -> bf16 [32768,320] ---------------
__global__ void convert_x_kernel(const float* __restrict__ X, ushort16* __restrict__ A0) {
  int row = blockIdx.x * 4 + (threadIdx.x >> 6);
  int lane = threadIdx.x & 63;
  const float* xr = X + (size_t)row * 300;
  ushort16* ar = A0 + (size_t)row * KPAD1;
#pragma unroll
  for (int i = 0; i < 5; ++i) {
    int col = lane + i * 64;
    float v = (col < 300) ? xr[col] : 0.f;
    ar[col] = f2bf(v);
  }
}

// ---------------- sentence mean partials: Hpart[4][64][768] -----------------
__global__ void sent_mean_kernel(const float* __restrict__ last,
                                 const float* __restrict__ first,
                                 float* __restrict__ Hpart) {
  int b = blockIdx.x, sc = blockIdx.y, e = threadIdx.x;  // block 768, grid (64,4)
  int s0 = sc * 128;
  const float* pl = last + ((size_t)b * 512 + s0) * 768 + e;
  const float* pf = first + ((size_t)b * 512 + s0) * 768 + e;
  float a0 = 0.f, a1 = 0.f, a2 = 0.f, a3 = 0.f;
  for (int i = 0; i < 128; i += 4) {
    a0 += pl[(i + 0) * 768] + pf[(i + 0) * 768];
    a1 += pl[(i + 1) * 768] + pf[(i + 1) * 768];
    a2 += pl[(i + 2) * 768] + pf[(i + 2) * 768];
    a3 += pl[(i + 3) * 768] + pf[(i + 3) * 768];
  }
  Hpart[((size_t)sc * 64 + b) * 768 + e] = a0 + a1 + a2 + a3;
}

// ---------------- degree / CSR build ----------------------------------------
__global__ void deg_count_kernel(const int* __restrict__ dst, int* __restrict__ cnt, int E) {
  int e = blockIdx.x * blockDim.x + threadIdx.x;
  if (e < E) atomicAdd(&cnt[dst[e]], 1);
}
// single-block scan; also computes disq (fold of old disq_kernel)
__global__ void scan_kernel(const int* __restrict__ cnt, int* __restrict__ row_start,
                            int* __restrict__ cursor, float* __restrict__ disq) {
  __shared__ int buf[1024];
  int t = threadIdx.x;
  int base = t * 32;
  int lc[32];
  int s = 0;
  for (int i = 0; i < 32; ++i) { lc[i] = cnt[base + i]; s += lc[i]; }
  buf[t] = s; __syncthreads();
  int x = s;
  for (int off = 1; off < 1024; off <<= 1) {
    int v = (t >= off) ? buf[t - off] : 0;
    __syncthreads();
    x += v; buf[t] = x;
    __syncthreads();
  }
  int run = x - s;
  for (int i = 0; i < 32; ++i) {
    row_start[base + i] = run; cursor[base + i] = run;
    disq[base + i] = rsqrtf((float)lc[i] + 1.0f);  // +1 self loop
    run += lc[i];
  }
  if (t == 1023) row_start[NNODES] = run;
}
// csr stores PRE-SCALED row offsets: src*192 (dword offset of source row)
__global__ void scatter_kernel(const int* __restrict__ src, const int* __restrict__ dst,
                               int* __restrict__ cursor, int* __restrict__ csr, int E) {
  int e = blockIdx.x * blockDim.x + threadIdx.x;
  if (e < E) {
    int d = dst[e];
    int pos = atomicAdd(&cursor[d], 1);
    csr[pos] = src[e] * 192;
  }
}

// ---------------- weight transform, LDS-staged (coalesced W reads) ----------
// BT[n][k] = a_k*W[k][n] bf16;  bias_out[n] = bias[n] + sum_k sh_k*W[k][n]
// grid: 6 blocks (64 n each), 256 threads; each block loops all K.
__global__ void xform_w_kernel(const float* __restrict__ W, const float* __restrict__ bias,
                               const float* __restrict__ stat, const float* __restrict__ g,
                               const float* __restrict__ bb, float invN,
                               ushort16* __restrict__ BT, float* __restrict__ bias_out,
                               int K, int Kpad) {
  __shared__ float tile[64 * 65];
  __shared__ float la[64], lsh[64];
  __shared__ float psum[4][64];
  const int Nw = DFEAT;
  int n0 = blockIdx.x * 64;
  int t = threadIdx.x;
  int nn = t & 63, r = t >> 6;  // r in [0,4)
  float part = 0.f;
  for (int k0 = 0; k0 < Kpad; k0 += 64) {
    if (t < 64) {
      int k = k0 + t;
      float ak = 0.f, shk = 0.f;
      if (k < K) {
        ak = 1.f;
        if (stat) {
          float s = 0.f, q = 0.f;
          for (int i = 0; i < 8; ++i) { s += stat[k * 8 + i]; q += stat[(DFEAT + k) * 8 + i]; }
          float mean = s * invN, var = q * invN - mean * mean;
          ak = g[k] * rsqrtf(var + 1e-5f);
          shk = bb[k] - ak * mean;
        }
      }
      la[t] = ak; lsh[t] = shk;
    }
    __syncthreads();
    for (int rr = r; rr < 64; rr += 4) {
      int k = k0 + rr;
      tile[rr * 65 + nn] = (k < K) ? W[(size_t)k * Nw + n0 + nn] : 0.f;
    }
    __syncthreads();
    for (int i = 0; i < 16; ++i) {
      int kk = r + 4 * i;
      float w = tile[kk * 65 + nn];
      BT[(size_t)(n0 + nn) * Kpad + k0 + kk] = f2bf(la[kk] * w);
      part += lsh[kk] * w;
    }
    __syncthreads();
  }
  psum[r][nn] = part;
  __syncthreads();
  if (t < 64) {
    bias_out[n0 + t] = (bias ? bias[n0 + t] : 0.f) +
                       psum[0][t] + psum[1][t] + psum[2][t] + psum[3][t];
  }
}

// ---------------- MFMA bf16 GEMM with fused stats / row-scale ---------------
#define BM 128
#define BN 128
#define BKT 32
#define LDT 40  // BKT + 8 pad shorts

template <bool RELU, bool STATS, bool RSCALE>
__global__ __launch_bounds__(256) void gemm_bf16(
    const ushort16* __restrict__ A, int lda, const ushort16* __restrict__ BT, int ldb,
    const float* __restrict__ bias, const float* __restrict__ rowscale,
    ushort16* __restrict__ C, int Ntot, int K, float* __restrict__ stat) {
  __shared__ __attribute__((aligned(16))) ushort16 As[BM * LDT];
  __shared__ __attribute__((aligned(16))) ushort16 Bs[BN * LDT];
  __shared__ float ssum[BN], ssq[BN];
  int bm0 = blockIdx.x * BM, bn0 = blockIdx.y * BN;
  int tid = threadIdx.x;
  if (STATS) {
    if (tid < BN) { ssum[tid] = 0.f; ssq[tid] = 0.f; }
  }
  int lane = tid & 63, wave = tid >> 6;
  int wm = (wave & 1) * 64, wn = (wave >> 1) * 64;
  int l15 = lane & 15, quad = lane >> 4;

  f32x4 acc[4][4];
  for (int i = 0; i < 4; ++i)
    for (int j = 0; j < 4; ++j) acc[i][j] = (f32x4)0.f;

  for (int kk = 0; kk < K; kk += BKT) {
    __syncthreads();
    for (int i = 0; i < 2; ++i) {
      int chunk = tid + i * 256;
      int row = chunk >> 2, cc = chunk & 3;
      uint4 va = *(const uint4*)(A + (size_t)(bm0 + row) * lda + kk + cc * 8);
      *(uint4*)(&As[row * LDT + cc * 8]) = va;
      uint4 vb = *(const uint4*)(BT + (size_t)(bn0 + row) * ldb + kk + cc * 8);
      *(uint4*)(&Bs[row * LDT + cc * 8]) = vb;
    }
    __syncthreads();
    bf16x8 af[4], bfr[4];
    for (int mi = 0; mi < 4; ++mi)
      af[mi] = *(const bf16x8*)(&As[(wm + mi * 16 + l15) * LDT + quad * 8]);
    for (int ni = 0; ni < 4; ++ni)
      bfr[ni] = *(const bf16x8*)(&Bs[(wn + ni * 16 + l15) * LDT + quad * 8]);
    for (int mi = 0; mi < 4; ++mi)
      for (int ni = 0; ni < 4; ++ni)
        acc[mi][ni] = __builtin_amdgcn_mfma_f32_16x16x32_bf16(af[mi], bfr[ni], acc[mi][ni], 0, 0, 0);
  }
  for (int ni = 0; ni < 4; ++ni) {
    int coll = wn + ni * 16 + l15;
    int col = bn0 + coll;
    float bv = bias[col];
    float s = 0.f, q = 0.f;
    for (int mi = 0; mi < 4; ++mi) {
      for (int r = 0; r < 4; ++r) {
        int row = bm0 + wm + mi * 16 + quad * 4 + r;
        float v = acc[mi][ni][r] + bv;
        if (RELU) v = fmaxf(v, 0.f);
        if (RSCALE) v *= rowscale[row];
        C[(size_t)row * Ntot + col] = f2bf(v);
        if (STATS) { s += v; q += v * v; }
      }
    }
    if (STATS) { atomicAdd(&ssum[coll], s); atomicAdd(&ssq[coll], q); }
  }
  if (STATS) {
    __syncthreads();
    int sp = blockIdx.x & 7;
    if (tid < BN) {
      atomicAdd(&stat[(bn0 + tid) * 8 + sp], ssum[tid]);
      atomicAdd(&stat[(DFEAT + bn0 + tid) * 8 + sp], ssq[tid]);
    }
  }
}

// ---------------- GCN aggregation: scalar-addressed, 3x128-col chunks -------
// XWs rows prescaled by disq: RC[n] = relu(disq[n]*(XWs[n] + sum_s XWs[s]) + b)
// One wave per node; node id is wave-uniform (readfirstlane) so row_start/csr
// reads become s_loads and gather bases live in SGPRs. csr holds src*192.
// XCD slots: {0,1,2}->chunk0 thirds, {3,4,5}->chunk1 thirds, {6,7}->chunk2;
// chunk2's nodes are spread over all 8 slots for perfect balance (12288/slot).
#define AGG_BPS 128  // blocks per slot
__global__ __launch_bounds__(256) void aggregate_kernel(
    const uint32* __restrict__ XWs, const int* __restrict__ csr,
    const int* __restrict__ row_start, const float* __restrict__ disq,
    const float* __restrict__ bconv, uint32* __restrict__ RC2,
    float* __restrict__ stat) {
  int bx = blockIdx.x;
  int slot = bx & 7, g = bx >> 3;
  int wave = __builtin_amdgcn_readfirstlane((int)(threadIdx.x >> 6));
  int lane = threadIdx.x & 63;
  int seg_chunk[2], seg_start[2], seg_cnt[2];
  int nseg;
  if (slot < 6) {
    int m = slot / 3, part = slot % 3;
    seg_chunk[0] = m;
    seg_start[0] = part * 10923;
    seg_cnt[0] = (part == 2) ? 10922 : 10923;
    seg_chunk[1] = 2;
    seg_start[1] = slot * 1365;
    seg_cnt[1] = 1365;
    nseg = 2;
  } else {
    seg_chunk[0] = 2;
    seg_start[0] = 8190 + (slot - 6) * 12289;
    seg_cnt[0] = 12289;
    nseg = 1;
  }
  int vtot = seg_cnt[0] + ((nseg > 1) ? seg_cnt[1] : 0);
  int tw = AGG_BPS * 4;
  int wid = g * 4 + wave;
  int per = (vtot + tw - 1) / tw;
  int v0 = wid * per, v1 = min(vtot, v0 + per);
  int segbase = 0;
  for (int si = 0; si < nseg; ++si) {
    int s0 = max(v0 - segbase, 0);
    int s1 = min(v1 - segbase, seg_cnt[si]);
    segbase += seg_cnt[si];
    if (s0 >= s1) continue;
    int chunk = seg_chunk[si];
    const uint32* __restrict__ XWc = XWs + chunk * 64;
    int c0 = chunk * 128 + 2 * lane;
    float bias0 = bconv[c0], bias1 = bconv[c0 + 1];
    float ss0 = 0.f, ss1 = 0.f, qq0 = 0.f, qq1 = 0.f;
    int nA = seg_start[si] + s0, nB = seg_start[si] + s1;
    for (int n = nA; n < nB; ++n) {
      int beg = row_start[n], end = row_start[n + 1];
      uint32 v = XWc[(size_t)n * 192 + lane];  // self (prescaled)
      float a0 = bflo(v), a1 = bfhi(v);
      int j = beg;
      for (; j + 8 <= end; j += 8) {
        uint32 w[8];
#pragma unroll
        for (int t = 0; t < 8; ++t) w[t] = XWc[(size_t)(uint32)csr[j + t] + lane];
#pragma unroll
        for (int t = 0; t < 8; ++t) { a0 += bflo(w[t]); a1 += bfhi(w[t]); }
      }
      for (; j < end; ++j) {
        uint32 w = XWc[(size_t)(uint32)csr[j] + lane];
        a0 += bflo(w); a1 += bfhi(w);
      }
      float dn = disq[n];
      a0 = fmaxf(fmaf(dn, a0, bias0), 0.f);
      a1 = fmaxf(fmaf(dn, a1, bias1), 0.f);
      RC2[(size_t)n * 192 + chunk * 64 + lane] = (uint32)f2bf(a0) | ((uint32)f2bf(a1) << 16);
      ss0 += a0; qq0 += a0 * a0; ss1 += a1; qq1 += a1 * a1;
    }
    int sp = g & 7;
    atomicAdd(&stat[c0 * 8 + sp], ss0);
    atomicAdd(&stat[(DFEAT + c0) * 8 + sp], qq0);
    atomicAdd(&stat[(c0 + 1) * 8 + sp], ss1);
    atomicAdd(&stat[(DFEAT + c0 + 1) * 8 + sp], qq1);
  }
}

// ---------------- fused gather(+BN6) + cat GEMM -----------------------------
// grid (6 j-tiles, 8 b-tiles) x 1024; LDS holds 8 normalized flat rows.
__global__ __launch_bounds__(1024) void catgather_kernel(
    const int* __restrict__ mask, const ushort16* __restrict__ R5,
    const float* __restrict__ stat, const float* __restrict__ g6,
    const float* __restrict__ b6, float invN,
    const float* __restrict__ Wc, const float* __restrict__ bc,
    float* __restrict__ catrelu) {
  __shared__ float frow[8][768];
  __shared__ int smin[8], smax[8];
  int t = threadIdx.x;
  int jt = blockIdx.x, bt = blockIdx.y;
  if (t < 8) { smin[t] = 1 << 30; smax[t] = -1; }
  __syncthreads();
  for (int idx = t; idx < 8 * 512; idx += 1024) {
    int bl = idx >> 9, p = idx & 511;
    if (mask[(bt * 8 + bl) * 512 + p]) { atomicMin(&smin[bl], p); atomicMax(&smax[bl], p); }
  }
  __syncthreads();
  if (t < 768) {
    int cp = (t >= 384) ? t - 384 : t;
    int j = (t >= 384) ? 1 : 0;
    float s = 0.f, q = 0.f;
    for (int i = 0; i < 8; ++i) { s += stat[cp * 8 + i]; q += stat[(DFEAT + cp) * 8 + i]; }
    float mean = s * invN, var = q * invN - mean * mean;
    float a = g6[cp] * rsqrtf(var + 1e-5f), sh = b6[cp] - a * mean;
    for (int bl = 0; bl < 8; ++bl) {
      int gb = bt * 8 + bl;
      int sel = j ? smax[bl] : smin[bl];
      frow[bl][t] = a * bf2f(R5[(size_t)(gb * 512 + sel) * DFEAT + cp]) + sh;
    }
  }
  __syncthreads();
  int jj = jt * 128 + (t & 127), bl = t >> 7;
  float acc = bc[jj];
  const float* fr = frow[bl];
#pragma unroll 4
  for (int k = 0; k < 768; ++k) acc = fmaf(fr[k], Wc[(size_t)k * 768 + jj], acc);
  catrelu[(size_t)(bt * 8 + bl) * 768 + jj] = fmaxf(acc, 0.f);
}

// ---------------- batch-BN affines + Hsent fold; grid 12 x 64 ---------------
__global__ void bnstats_kernel(const float* __restrict__ catrelu, const float* __restrict__ Hpart,
                               float* __restrict__ Hsent,
                               const float* __restrict__ g, const float* __restrict__ bb,
                               float* __restrict__ aff) {
  int c = blockIdx.x * 64 + threadIdx.x;
  float s1 = 0, q1 = 0, s2 = 0, q2 = 0;
  for (int b = 0; b < 64; ++b) {
    float v = catrelu[b * 768 + c]; s1 += v; q1 += v * v;
    float h = Hpart[((size_t)0 * 64 + b) * 768 + c] + Hpart[((size_t)1 * 64 + b) * 768 + c] +
              Hpart[((size_t)2 * 64 + b) * 768 + c] + Hpart[((size_t)3 * 64 + b) * 768 + c];
    h *= (0.5f / 512.f);
    Hsent[(size_t)b * 768 + c] = h;
    s2 += h; q2 += h * h;
  }
  const float inv = 1.0f / 64.0f;
  float m1 = s1 * inv, var1 = q1 * inv - m1 * m1;
  float a1 = g[c] * rsqrtf(var1 + 1e-5f);
  aff[c] = a1; aff[768 + c] = bb[c] - a1 * m1;
  float m2 = s2 * inv, var2 = q2 * inv - m2 * m2;
  float a2 = g[768 + c] * rsqrtf(var2 + 1e-5f);
  aff[1536 + c] = a2; aff[2304 + c] = bb[768 + c] - a2 * m2;
}

__global__ void final_kernel(const float* __restrict__ Hs, const float* __restrict__ catrelu,
                             const float* __restrict__ aff, const float* __restrict__ w_out,
                             const float* __restrict__ b_out, float* __restrict__ out) {
  __shared__ float red[12];
  int b = blockIdx.x, t = threadIdx.x;  // 256
  float p0 = 0, p1 = 0, p2 = 0;
  for (int k = t; k < 768; k += 256) {
    float att = (aff[1536 + k] * Hs[b * 768 + k] + aff[2304 + k]) +
                (aff[k] * catrelu[b * 768 + k] + aff[768 + k]);
    p0 += att * w_out[k * 3 + 0];
    p1 += att * w_out[k * 3 + 1];
    p2 += att * w_out[k * 3 + 2];
  }
  for (int off = 32; off > 0; off >>= 1) {
    p0 += __shfl_down(p0, off, 64);
    p1 += __shfl_down(p1, off, 64);
    p2 += __shfl_down(p2, off, 64);
  }
  int wv = t >> 6;
  if ((t & 63) == 0) { red[wv * 3 + 0] = p0; red[wv * 3 + 1] = p1; red[wv * 3 + 2] = p2; }
  __syncthreads();
  if (t == 0) {
    out[b * 3 + 0] = b_out[0] + red[0] + red[3] + red[6] + red[9];
    out[b * 3 + 1] = b_out[1] + red[1] + red[4] + red[7] + red[10];
    out[b * 3 + 2] = b_out[2] + red[2] + red[5] + red[8] + red[11];
  }
}

// ============================================================================
extern "C" void kernel_launch(void* const* d_in, const int* in_sizes, int n_in,
                              void* d_out, int out_size, void* d_ws, size_t ws_size,
                              hipStream_t stream) {
  const float* last_h  = (const float*)d_in[0];
  const float* first_h = (const float*)d_in[1];
  const float* x_nodes = (const float*)d_in[2];
  const int*   edges   = (const int*)d_in[3];
  const int*   mask    = (const int*)d_in[4];
  const float* w_pre1  = (const float*)d_in[5];
  const float* b_pre1  = (const float*)d_in[6];
  const float* w_pre2  = (const float*)d_in[7];
  const float* b_pre2  = (const float*)d_in[8];
  const float* w_conv  = (const float*)d_in[9];
  const float* b_conv  = (const float*)d_in[10];
  const float* bng_g   = (const float*)d_in[11];
  const float* bng_b   = (const float*)d_in[12];
  const float* w_post1 = (const float*)d_in[13];
  const float* b_post1 = (const float*)d_in[14];
  const float* w_post2 = (const float*)d_in[15];
  const float* b_post2 = (const float*)d_in[16];
  const float* w_cat   = (const float*)d_in[17];
  const float* b_cat   = (const float*)d_in[18];
  const float* bn_g    = (const float*)d_in[19];
  const float* bn_b    = (const float*)d_in[20];
  const float* w_out   = (const float*)d_in[21];
  const float* b_out   = (const float*)d_in[22];
  float* out = (float*)d_out;

  const int E = in_sizes[3] / 2;  // 1048576
  const int* e_src = edges;
  const int* e_dst = edges + E;

  char* w = (char*)d_ws;
  size_t off = 0;
  auto alloc = [&](size_t bytes) { size_t p = off; off = (off + bytes + 255) & ~(size_t)255; return p; };
  ushort16* buf0   = (ushort16*)(w + alloc((size_t)NNODES * DFEAT * 2));  // A0, R2, RC, R5
  ushort16* buf1   = (ushort16*)(w + alloc((size_t)NNODES * DFEAT * 2));  // R1, XW', R4
  int*    csr      = (int*)(w + alloc((size_t)E * 4));
  int*    rowstart = (int*)(w + alloc((size_t)(NNODES + 1) * 4));
  int*    cursor   = (int*)(w + alloc((size_t)NNODES * 4));
  float*  disq     = (float*)(w + alloc((size_t)NNODES * 4));
  ushort16* BT     = (ushort16*)(w + alloc((size_t)DFEAT * DFEAT * 2));
  float*  biasx    = (float*)(w + alloc(DFEAT * 4));
  float*  catrelu  = (float*)(w + alloc(64 * 768 * 4));
  float*  aff64    = (float*)(w + alloc(4 * 768 * 4));
  float*  Hpart    = (float*)(w + alloc((size_t)4 * 64 * 768 * 4));
  float*  Hsent    = (float*)(w + alloc(64 * 768 * 4));
  size_t zoff = off;
  int*   degcnt = (int*)(w + alloc((size_t)NNODES * 4));
  float* stats  = (float*)(w + alloc((size_t)5 * 768 * 8 * 4));
  size_t zbytes = off - zoff;

  hipMemsetAsync(w + zoff, 0, zbytes, stream);

  const float invN = 1.0f / (float)NNODES;
  float* st0 = stats + 0 * 768 * 8;
  float* st1 = stats + 1 * 768 * 8;
  float* st2 = stats + 2 * 768 * 8;
  float* st3 = stats + 3 * 768 * 8;
  float* st4 = stats + 4 * 768 * 8;

  // ---- prep ----
  convert_x_kernel<<<NNODES / 4, 256, 0, stream>>>(x_nodes, buf0);
  xform_w_kernel<<<6, 256, 0, stream>>>(w_pre1, b_pre1, nullptr, nullptr, nullptr, invN, BT, biasx, 300, KPAD1);
  sent_mean_kernel<<<dim3(64, 4), 768, 0, stream>>>(last_h, first_h, Hpart);
  deg_count_kernel<<<(E + 255) / 256, 256, 0, stream>>>(e_dst, degcnt, E);
  scan_kernel<<<1, 1024, 0, stream>>>(degcnt, rowstart, cursor, disq);
  scatter_kernel<<<(E + 255) / 256, 256, 0, stream>>>(e_src, e_dst, cursor, csr, E);

  dim3 ggrid(NNODES / BM, DFEAT / BN);

  // ---- GEMM1: R1 = relu(x @ W1 + b1), stats->BN0 ----
  gemm_bf16<true, true, false><<<ggrid, 256, 0, stream>>>(buf0, KPAD1, BT, KPAD1, biasx, nullptr, buf1, DFEAT, KPAD1, st0);
  xform_w_kernel<<<6, 256, 0, stream>>>(w_pre2, b_pre2, st0, bng_g + 0 * DFEAT, bng_b + 0 * DFEAT, invN, BT, biasx, DFEAT, DFEAT);

  // ---- GEMM2: R2 = relu(BN0(R1) @ W2 + b2), stats->BN1 ----
  gemm_bf16<true, true, false><<<ggrid, 256, 0, stream>>>(buf1, DFEAT, BT, DFEAT, biasx, nullptr, buf0, DFEAT, DFEAT, st1);
  xform_w_kernel<<<6, 256, 0, stream>>>(w_conv + 2 * DFEAT * DFEAT, nullptr, st1, bng_g + 1 * DFEAT, bng_b + 1 * DFEAT, invN, BT, biasx, DFEAT, DFEAT);

  // ---- GEMM3: XW' = disq[row] * (BN1(R2) @ Wc)  (conv i=2 only survives) ----
  gemm_bf16<false, false, true><<<ggrid, 256, 0, stream>>>(buf0, DFEAT, BT, DFEAT, biasx, disq, buf1, DFEAT, DFEAT, nullptr);

  // ---- aggregation (scalar-addressed, 3 chunks, balanced slots) ----
  aggregate_kernel<<<8 * AGG_BPS, 256, 0, stream>>>((const uint32*)buf1, csr, rowstart, disq, b_conv + 2 * DFEAT, (uint32*)buf0, st2);
  xform_w_kernel<<<6, 256, 0, stream>>>(w_post1, b_post1, st2, bng_g + 4 * DFEAT, bng_b + 4 * DFEAT, invN, BT, biasx, DFEAT, DFEAT);

  // ---- GEMM4: R4 = relu(BN4(RC) @ Wp1 + bp1), stats->BN5 ----
  gemm_bf16<true, true, false><<<ggrid, 256, 0, stream>>>(buf0, DFEAT, BT, DFEAT, biasx, nullptr, buf1, DFEAT, DFEAT, st3);
  xform_w_kernel<<<6, 256, 0, stream>>>(w_post2, b_post2, st3, bng_g + 5 * DFEAT, bng_b + 5 * DFEAT, invN, BT, biasx, DFEAT, DFEAT);

  // ---- GEMM5: R5 = relu(BN5(R4) @ Wp2 + bp2), stats->BN6 ----
  gemm_bf16<true, true, false><<<ggrid, 256, 0, stream>>>(buf1, DFEAT, BT, DFEAT, biasx, nullptr, buf0, DFEAT, DFEAT, st4);

  // ---- fused gather+cat, BN affines, output ----
  catgather_kernel<<<dim3(6, 8), 1024, 0, stream>>>(mask, buf0, st4, bng_g + 6 * DFEAT, bng_b + 6 * DFEAT, invN, w_cat, b_cat, catrelu);
  bnstats_kernel<<<12, 64, 0, stream>>>(catrelu, Hpart, Hsent, bn_g, bn_b, aff64);
  final_kernel<<<64, 256, 0, stream>>>(Hsent, catrelu, aff64, w_out, b_out, out);
}

// Round 5
// 969.368 us; speedup vs baseline: 1.2382x; 1.2382x over previous
//
#include <hip/hip_runtime.h>

typedef unsigned int uint32;
typedef unsigned short ushort16;

typedef __attribute__((ext_vector_type(8))) short bf16x8;
typedef __attribute__((ext_vector_type(4))) float f32x4;

#define NNODES 32768
#define DFEAT 384
#define KPAD1 320

__device__ __forceinline__ float bf2f(ushort16 u) {
  union { uint32 i; float f; } x; x.i = ((uint32)u) << 16; return x.f;
}
__device__ __forceinline__ float bflo(uint32 v) {
  union { uint32 i; float f; } x; x.i = v << 16; return x.f;
}
__device__ __forceinline__ float bfhi(uint32 v) {
  union { uint32 i; float f; } x; x.i = v & 0xffff0000u; return x.f;
}
__device__ __forceinline__ ushort16 f2bf(float f) {
  union { float f; uint32 i; } x; x.f = f;
  uint32 r = (x.i + 0x7fffu + ((x.i >> 16) & 1u)) >> 16;
  return (ushort16)r;
}

// ---------------- x_nodes f32 [32768,300] -> bf16 [32768,320] ---------------
__global__ void convert_x_kernel(const float* __restrict__ X, ushort16* __restrict__ A0) {
  int row = blockIdx.x * 4 + (threadIdx.x >> 6);
  int lane = threadIdx.x & 63;
  const float* xr = X + (size_t)row * 300;
  ushort16* ar = A0 + (size_t)row * KPAD1;
#pragma unroll
  for (int i = 0; i < 5; ++i) {
    int col = lane + i * 64;
    float v = (col < 300) ? xr[col] : 0.f;
    ar[col] = f2bf(v);
  }
}

// ---------------- sentence mean partials: Hpart[4][64][768] -----------------
__global__ void sent_mean_kernel(const float* __restrict__ last,
                                 const float* __restrict__ first,
                                 float* __restrict__ Hpart) {
  int b = blockIdx.x, sc = blockIdx.y, e = threadIdx.x;  // block 768, grid (64,4)
  int s0 = sc * 128;
  const float* pl = last + ((size_t)b * 512 + s0) * 768 + e;
  const float* pf = first + ((size_t)b * 512 + s0) * 768 + e;
  float a0 = 0.f, a1 = 0.f, a2 = 0.f, a3 = 0.f;
  for (int i = 0; i < 128; i += 4) {
    a0 += pl[(i + 0) * 768] + pf[(i + 0) * 768];
    a1 += pl[(i + 1) * 768] + pf[(i + 1) * 768];
    a2 += pl[(i + 2) * 768] + pf[(i + 2) * 768];
    a3 += pl[(i + 3) * 768] + pf[(i + 3) * 768];
  }
  Hpart[((size_t)sc * 64 + b) * 768 + e] = a0 + a1 + a2 + a3;
}

// ---------------- degree / CSR build ----------------------------------------
__global__ void deg_count_kernel(const int* __restrict__ dst, int* __restrict__ cnt, int E) {
  int e = blockIdx.x * blockDim.x + threadIdx.x;
  if (e < E) atomicAdd(&cnt[dst[e]], 1);
}
// single-block scan; also computes disq
__global__ void scan_kernel(const int* __restrict__ cnt, int* __restrict__ row_start,
                            int* __restrict__ cursor, float* __restrict__ disq) {
  __shared__ int buf[1024];
  int t = threadIdx.x;
  int base = t * 32;
  int lc[32];
  int s = 0;
  for (int i = 0; i < 32; ++i) { lc[i] = cnt[base + i]; s += lc[i]; }
  buf[t] = s; __syncthreads();
  int x = s;
  for (int off = 1; off < 1024; off <<= 1) {
    int v = (t >= off) ? buf[t - off] : 0;
    __syncthreads();
    x += v; buf[t] = x;
    __syncthreads();
  }
  int run = x - s;
  for (int i = 0; i < 32; ++i) {
    row_start[base + i] = run; cursor[base + i] = run;
    disq[base + i] = rsqrtf((float)lc[i] + 1.0f);  // +1 self loop
    run += lc[i];
  }
  if (t == 1023) row_start[NNODES] = run;
}
// csr stores PRE-SCALED row offsets: src*192 (uint32 offset of source row)
__global__ void scatter_kernel(const int* __restrict__ src, const int* __restrict__ dst,
                               int* __restrict__ cursor, int* __restrict__ csr, int E) {
  int e = blockIdx.x * blockDim.x + threadIdx.x;
  if (e < E) {
    int d = dst[e];
    int pos = atomicAdd(&cursor[d], 1);
    csr[pos] = src[e] * 192;
  }
}

// ---------------- weight transform (R3 version: 384 blocks, coalesced) ------
// BT[n][k] = a_k*W[k][n] bf16;  bias_out[n] = bias[n] + sum_k sh_k*W[k][n]
__global__ void xform_w_kernel(const float* __restrict__ W, const float* __restrict__ bias,
                               const float* __restrict__ stat, const float* __restrict__ g,
                               const float* __restrict__ bb, float invN,
                               ushort16* __restrict__ BT, float* __restrict__ bias_out,
                               int K, int Kpad) {
  __shared__ float red[128];
  const int Nw = DFEAT;
  int n = blockIdx.x, t = threadIdx.x;
  float part = 0.f;
  for (int k = t; k < Kpad; k += 128) {
    ushort16 o = 0; float contrib = 0.f;
    if (k < K) {
      float ak = 1.f, shk = 0.f;
      if (stat) {
        float s = 0.f, q = 0.f;
        for (int i = 0; i < 8; ++i) { s += stat[k * 8 + i]; q += stat[(DFEAT + k) * 8 + i]; }
        float mean = s * invN, var = q * invN - mean * mean;
        ak = g[k] * rsqrtf(var + 1e-5f);
        shk = bb[k] - ak * mean;
      }
      float w = W[(size_t)k * Nw + n];
      o = f2bf(ak * w);
      contrib = shk * w;
    }
    BT[(size_t)n * Kpad + k] = o;
    part += contrib;
  }
  red[t] = part; __syncthreads();
  for (int off = 64; off > 0; off >>= 1) {
    if (t < off) red[t] += red[t + off];
    __syncthreads();
  }
  if (t == 0) bias_out[n] = (bias ? bias[n] : 0.f) + red[0];
}

// ---------------- MFMA bf16 GEMM with fused stats / row-scale ---------------
#define BM 128
#define BN 128
#define BKT 32
#define LDT 40  // BKT + 8 pad shorts

template <bool RELU, bool STATS, bool RSCALE>
__global__ __launch_bounds__(256) void gemm_bf16(
    const ushort16* __restrict__ A, int lda, const ushort16* __restrict__ BT, int ldb,
    const float* __restrict__ bias, const float* __restrict__ rowscale,
    ushort16* __restrict__ C, int Ntot, int K, float* __restrict__ stat) {
  __shared__ __attribute__((aligned(16))) ushort16 As[BM * LDT];
  __shared__ __attribute__((aligned(16))) ushort16 Bs[BN * LDT];
  __shared__ float ssum[BN], ssq[BN];
  int bm0 = blockIdx.x * BM, bn0 = blockIdx.y * BN;
  int tid = threadIdx.x;
  if (STATS) {
    if (tid < BN) { ssum[tid] = 0.f; ssq[tid] = 0.f; }
  }
  int lane = tid & 63, wave = tid >> 6;
  int wm = (wave & 1) * 64, wn = (wave >> 1) * 64;
  int l15 = lane & 15, quad = lane >> 4;

  f32x4 acc[4][4];
  for (int i = 0; i < 4; ++i)
    for (int j = 0; j < 4; ++j) acc[i][j] = (f32x4)0.f;

  for (int kk = 0; kk < K; kk += BKT) {
    __syncthreads();
    for (int i = 0; i < 2; ++i) {
      int chunk = tid + i * 256;
      int row = chunk >> 2, cc = chunk & 3;
      uint4 va = *(const uint4*)(A + (size_t)(bm0 + row) * lda + kk + cc * 8);
      *(uint4*)(&As[row * LDT + cc * 8]) = va;
      uint4 vb = *(const uint4*)(BT + (size_t)(bn0 + row) * ldb + kk + cc * 8);
      *(uint4*)(&Bs[row * LDT + cc * 8]) = vb;
    }
    __syncthreads();
    bf16x8 af[4], bfr[4];
    for (int mi = 0; mi < 4; ++mi)
      af[mi] = *(const bf16x8*)(&As[(wm + mi * 16 + l15) * LDT + quad * 8]);
    for (int ni = 0; ni < 4; ++ni)
      bfr[ni] = *(const bf16x8*)(&Bs[(wn + ni * 16 + l15) * LDT + quad * 8]);
    for (int mi = 0; mi < 4; ++mi)
      for (int ni = 0; ni < 4; ++ni)
        acc[mi][ni] = __builtin_amdgcn_mfma_f32_16x16x32_bf16(af[mi], bfr[ni], acc[mi][ni], 0, 0, 0);
  }
  for (int ni = 0; ni < 4; ++ni) {
    int coll = wn + ni * 16 + l15;
    int col = bn0 + coll;
    float bv = bias[col];
    float s = 0.f, q = 0.f;
    for (int mi = 0; mi < 4; ++mi) {
      for (int r = 0; r < 4; ++r) {
        int row = bm0 + wm + mi * 16 + quad * 4 + r;
        float v = acc[mi][ni][r] + bv;
        if (RELU) v = fmaxf(v, 0.f);
        if (RSCALE) v *= rowscale[row];
        C[(size_t)row * Ntot + col] = f2bf(v);
        if (STATS) { s += v; q += v * v; }
      }
    }
    if (STATS) { atomicAdd(&ssum[coll], s); atomicAdd(&ssq[coll], q); }
  }
  if (STATS) {
    __syncthreads();
    int sp = blockIdx.x & 7;
    if (tid < BN) {
      atomicAdd(&stat[(bn0 + tid) * 8 + sp], ssum[tid]);
      atomicAdd(&stat[(DFEAT + bn0 + tid) * 8 + sp], ssq[tid]);
    }
  }
}

// ---------------- GCN aggregation: 8 chunks x 48 cols, scalar CSR -----------
// XWs rows prescaled by disq: RC[n] = relu(disq[n]*(XWs[n] + sum_s XWs[s]) + b)
// chunk = blockIdx%8 -> one XCD per chunk; working set 32768x96B = 3MB < L2.
// One wave per node (uniform via readfirstlane -> csr[j] is s_load).
// Lanes 0-23 process even edges, 32-55 odd edges; one load serves 2 edges.
#define AGG_BPS 192  // blocks per slot/chunk
__global__ __launch_bounds__(256) void aggregate_kernel(
    const uint32* __restrict__ XWs, const int* __restrict__ csr,
    const int* __restrict__ row_start, const float* __restrict__ disq,
    const float* __restrict__ bconv, uint32* __restrict__ RC2,
    float* __restrict__ stat) {
  int bx = blockIdx.x;
  int chunk = bx & 7, g = bx >> 3;
  int wave = __builtin_amdgcn_readfirstlane((int)(threadIdx.x >> 6));
  int lane = threadIdx.x & 63;
  int half = lane >> 5, cl = lane & 31;
  if (cl >= 24) return;
  int myoff = chunk * 24 + cl;       // uint32 offset within 192-uint32 row
  int c0 = chunk * 48 + 2 * cl;      // column pair base
  float bias0 = bconv[c0], bias1 = bconv[c0 + 1];
  const int TW = AGG_BPS * 4;
  int wid = g * 4 + wave;
  int per = (NNODES + TW - 1) / TW;  // 43
  int nA = wid * per, nB = min(NNODES, nA + per);
  float ls0 = 0.f, ls1 = 0.f, lq0 = 0.f, lq1 = 0.f;
  for (int n = nA; n < nB; ++n) {
    int beg = row_start[n], end = row_start[n + 1];
    uint32 sv = XWs[(size_t)n * 192 + myoff];  // self (prescaled)
    float a0, a1;
    if (half == 0) { a0 = bflo(sv); a1 = bfhi(sv); } else { a0 = 0.f; a1 = 0.f; }
    int pend = beg + ((end - beg) & ~1);
    int j = beg;
    for (; j + 8 <= pend; j += 8) {
      uint32 w[4];
#pragma unroll
      for (int t = 0; t < 4; ++t) {
        int sa = csr[j + 2 * t], sb = csr[j + 2 * t + 1];
        w[t] = XWs[(size_t)(uint32)(half ? sb : sa) + myoff];
      }
#pragma unroll
      for (int t = 0; t < 4; ++t) { a0 += bflo(w[t]); a1 += bfhi(w[t]); }
    }
    for (; j < pend; j += 2) {
      int sa = csr[j], sb = csr[j + 1];
      uint32 wv = XWs[(size_t)(uint32)(half ? sb : sa) + myoff];
      a0 += bflo(wv); a1 += bfhi(wv);
    }
    if (pend < end) {  // odd-degree tail: lower half only
      uint32 wv = XWs[(size_t)(uint32)csr[end - 1] + myoff];
      if (half == 0) { a0 += bflo(wv); a1 += bfhi(wv); }
    }
    a0 += __shfl_xor(a0, 32, 64);
    a1 += __shfl_xor(a1, 32, 64);
    if (half == 0) {
      float dn = disq[n];
      a0 = fmaxf(fmaf(dn, a0, bias0), 0.f);
      a1 = fmaxf(fmaf(dn, a1, bias1), 0.f);
      RC2[(size_t)n * 192 + myoff] = (uint32)f2bf(a0) | ((uint32)f2bf(a1) << 16);
      ls0 += a0; lq0 += a0 * a0; ls1 += a1; lq1 += a1 * a1;
    }
  }
  if (half == 0) {
    int sp = g & 7;
    atomicAdd(&stat[c0 * 8 + sp], ls0);
    atomicAdd(&stat[(DFEAT + c0) * 8 + sp], lq0);
    atomicAdd(&stat[(c0 + 1) * 8 + sp], ls1);
    atomicAdd(&stat[(DFEAT + c0 + 1) * 8 + sp], lq1);
  }
}

// ---------------- fused gather(+BN6) + cat GEMM -----------------------------
__global__ __launch_bounds__(1024) void catgather_kernel(
    const int* __restrict__ mask, const ushort16* __restrict__ R5,
    const float* __restrict__ stat, const float* __restrict__ g6,
    const float* __restrict__ b6, float invN,
    const float* __restrict__ Wc, const float* __restrict__ bc,
    float* __restrict__ catrelu) {
  __shared__ float frow[8][768];
  __shared__ int smin[8], smax[8];
  int t = threadIdx.x;
  int jt = blockIdx.x, bt = blockIdx.y;
  if (t < 8) { smin[t] = 1 << 30; smax[t] = -1; }
  __syncthreads();
  for (int idx = t; idx < 8 * 512; idx += 1024) {
    int bl = idx >> 9, p = idx & 511;
    if (mask[(bt * 8 + bl) * 512 + p]) { atomicMin(&smin[bl], p); atomicMax(&smax[bl], p); }
  }
  __syncthreads();
  if (t < 768) {
    int cp = (t >= 384) ? t - 384 : t;
    int j = (t >= 384) ? 1 : 0;
    float s = 0.f, q = 0.f;
    for (int i = 0; i < 8; ++i) { s += stat[cp * 8 + i]; q += stat[(DFEAT + cp) * 8 + i]; }
    float mean = s * invN, var = q * invN - mean * mean;
    float a = g6[cp] * rsqrtf(var + 1e-5f), sh = b6[cp] - a * mean;
    for (int bl = 0; bl < 8; ++bl) {
      int gb = bt * 8 + bl;
      int sel = j ? smax[bl] : smin[bl];
      frow[bl][t] = a * bf2f(R5[(size_t)(gb * 512 + sel) * DFEAT + cp]) + sh;
    }
  }
  __syncthreads();
  int jj = jt * 128 + (t & 127), bl = t >> 7;
  float acc = bc[jj];
  const float* fr = frow[bl];
#pragma unroll 4
  for (int k = 0; k < 768; ++k) acc = fmaf(fr[k], Wc[(size_t)k * 768 + jj], acc);
  catrelu[(size_t)(bt * 8 + bl) * 768 + jj] = fmaxf(acc, 0.f);
}

// ---------------- batch-BN affines + Hsent fold; grid 12 x 64 ---------------
__global__ void bnstats_kernel(const float* __restrict__ catrelu, const float* __restrict__ Hpart,
                               float* __restrict__ Hsent,
                               const float* __restrict__ g, const float* __restrict__ bb,
                               float* __restrict__ aff) {
  int c = blockIdx.x * 64 + threadIdx.x;
  float s1 = 0, q1 = 0, s2 = 0, q2 = 0;
  for (int b = 0; b < 64; ++b) {
    float v = catrelu[b * 768 + c]; s1 += v; q1 += v * v;
    float h = Hpart[((size_t)0 * 64 + b) * 768 + c] + Hpart[((size_t)1 * 64 + b) * 768 + c] +
              Hpart[((size_t)2 * 64 + b) * 768 + c] + Hpart[((size_t)3 * 64 + b) * 768 + c];
    h *= (0.5f / 512.f);
    Hsent[(size_t)b * 768 + c] = h;
    s2 += h; q2 += h * h;
  }
  const float inv = 1.0f / 64.0f;
  float m1 = s1 * inv, var1 = q1 * inv - m1 * m1;
  float a1 = g[c] * rsqrtf(var1 + 1e-5f);
  aff[c] = a1; aff[768 + c] = bb[c] - a1 * m1;
  float m2 = s2 * inv, var2 = q2 * inv - m2 * m2;
  float a2 = g[768 + c] * rsqrtf(var2 + 1e-5f);
  aff[1536 + c] = a2; aff[2304 + c] = bb[768 + c] - a2 * m2;
}

__global__ void final_kernel(const float* __restrict__ Hs, const float* __restrict__ catrelu,
                             const float* __restrict__ aff, const float* __restrict__ w_out,
                             const float* __restrict__ b_out, float* __restrict__ out) {
  __shared__ float red[12];
  int b = blockIdx.x, t = threadIdx.x;  // 256
  float p0 = 0, p1 = 0, p2 = 0;
  for (int k = t; k < 768; k += 256) {
    float att = (aff[1536 + k] * Hs[b * 768 + k] + aff[2304 + k]) +
                (aff[k] * catrelu[b * 768 + k] + aff[768 + k]);
    p0 += att * w_out[k * 3 + 0];
    p1 += att * w_out[k * 3 + 1];
    p2 += att * w_out[k * 3 + 2];
  }
  for (int off = 32; off > 0; off >>= 1) {
    p0 += __shfl_down(p0, off, 64);
    p1 += __shfl_down(p1, off, 64);
    p2 += __shfl_down(p2, off, 64);
  }
  int wv = t >> 6;
  if ((t & 63) == 0) { red[wv * 3 + 0] = p0; red[wv * 3 + 1] = p1; red[wv * 3 + 2] = p2; }
  __syncthreads();
  if (t == 0) {
    out[b * 3 + 0] = b_out[0] + red[0] + red[3] + red[6] + red[9];
    out[b * 3 + 1] = b_out[1] + red[1] + red[4] + red[7] + red[10];
    out[b * 3 + 2] = b_out[2] + red[2] + red[5] + red[8] + red[11];
  }
}

// ============================================================================
extern "C" void kernel_launch(void* const* d_in, const int* in_sizes, int n_in,
                              void* d_out, int out_size, void* d_ws, size_t ws_size,
                              hipStream_t stream) {
  const float* last_h  = (const float*)d_in[0];
  const float* first_h = (const float*)d_in[1];
  const float* x_nodes = (const float*)d_in[2];
  const int*   edges   = (const int*)d_in[3];
  const int*   mask    = (const int*)d_in[4];
  const float* w_pre1  = (const float*)d_in[5];
  const float* b_pre1  = (const float*)d_in[6];
  const float* w_pre2  = (const float*)d_in[7];
  const float* b_pre2  = (const float*)d_in[8];
  const float* w_conv  = (const float*)d_in[9];
  const float* b_conv  = (const float*)d_in[10];
  const float* bng_g   = (const float*)d_in[11];
  const float* bng_b   = (const float*)d_in[12];
  const float* w_post1 = (const float*)d_in[13];
  const float* b_post1 = (const float*)d_in[14];
  const float* w_post2 = (const float*)d_in[15];
  const float* b_post2 = (const float*)d_in[16];
  const float* w_cat   = (const float*)d_in[17];
  const float* b_cat   = (const float*)d_in[18];
  const float* bn_g    = (const float*)d_in[19];
  const float* bn_b    = (const float*)d_in[20];
  const float* w_out   = (const float*)d_in[21];
  const float* b_out   = (const float*)d_in[22];
  float* out = (float*)d_out;

  const int E = in_sizes[3] / 2;  // 1048576
  const int* e_src = edges;
  const int* e_dst = edges + E;

  char* w = (char*)d_ws;
  size_t off = 0;
  auto alloc = [&](size_t bytes) { size_t p = off; off = (off + bytes + 255) & ~(size_t)255; return p; };
  ushort16* buf0   = (ushort16*)(w + alloc((size_t)NNODES * DFEAT * 2));  // A0, R2, RC, R5
  ushort16* buf1   = (ushort16*)(w + alloc((size_t)NNODES * DFEAT * 2));  // R1, XW', R4
  int*    csr      = (int*)(w + alloc((size_t)E * 4));
  int*    rowstart = (int*)(w + alloc((size_t)(NNODES + 1) * 4));
  int*    cursor   = (int*)(w + alloc((size_t)NNODES * 4));
  float*  disq     = (float*)(w + alloc((size_t)NNODES * 4));
  ushort16* BT     = (ushort16*)(w + alloc((size_t)DFEAT * DFEAT * 2));
  float*  biasx    = (float*)(w + alloc(DFEAT * 4));
  float*  catrelu  = (float*)(w + alloc(64 * 768 * 4));
  float*  aff64    = (float*)(w + alloc(4 * 768 * 4));
  float*  Hpart    = (float*)(w + alloc((size_t)4 * 64 * 768 * 4));
  float*  Hsent    = (float*)(w + alloc(64 * 768 * 4));
  size_t zoff = off;
  int*   degcnt = (int*)(w + alloc((size_t)NNODES * 4));
  float* stats  = (float*)(w + alloc((size_t)5 * 768 * 8 * 4));
  size_t zbytes = off - zoff;

  hipMemsetAsync(w + zoff, 0, zbytes, stream);

  const float invN = 1.0f / (float)NNODES;
  float* st0 = stats + 0 * 768 * 8;
  float* st1 = stats + 1 * 768 * 8;
  float* st2 = stats + 2 * 768 * 8;
  float* st3 = stats + 3 * 768 * 8;
  float* st4 = stats + 4 * 768 * 8;

  // ---- prep ----
  convert_x_kernel<<<NNODES / 4, 256, 0, stream>>>(x_nodes, buf0);
  xform_w_kernel<<<DFEAT, 128, 0, stream>>>(w_pre1, b_pre1, nullptr, nullptr, nullptr, invN, BT, biasx, 300, KPAD1);
  sent_mean_kernel<<<dim3(64, 4), 768, 0, stream>>>(last_h, first_h, Hpart);
  deg_count_kernel<<<(E + 255) / 256, 256, 0, stream>>>(e_dst, degcnt, E);
  scan_kernel<<<1, 1024, 0, stream>>>(degcnt, rowstart, cursor, disq);
  scatter_kernel<<<(E + 255) / 256, 256, 0, stream>>>(e_src, e_dst, cursor, csr, E);

  dim3 ggrid(NNODES / BM, DFEAT / BN);

  // ---- GEMM1: R1 = relu(x @ W1 + b1), stats->BN0 ----
  gemm_bf16<true, true, false><<<ggrid, 256, 0, stream>>>(buf0, KPAD1, BT, KPAD1, biasx, nullptr, buf1, DFEAT, KPAD1, st0);
  xform_w_kernel<<<DFEAT, 128, 0, stream>>>(w_pre2, b_pre2, st0, bng_g + 0 * DFEAT, bng_b + 0 * DFEAT, invN, BT, biasx, DFEAT, DFEAT);

  // ---- GEMM2: R2 = relu(BN0(R1) @ W2 + b2), stats->BN1 ----
  gemm_bf16<true, true, false><<<ggrid, 256, 0, stream>>>(buf1, DFEAT, BT, DFEAT, biasx, nullptr, buf0, DFEAT, DFEAT, st1);
  xform_w_kernel<<<DFEAT, 128, 0, stream>>>(w_conv + 2 * DFEAT * DFEAT, nullptr, st1, bng_g + 1 * DFEAT, bng_b + 1 * DFEAT, invN, BT, biasx, DFEAT, DFEAT);

  // ---- GEMM3: XW' = disq[row] * (BN1(R2) @ Wc)  (conv i=2 only survives) ----
  gemm_bf16<false, false, true><<<ggrid, 256, 0, stream>>>(buf0, DFEAT, BT, DFEAT, biasx, disq, buf1, DFEAT, DFEAT, nullptr);

  // ---- aggregation (8x48-col chunks, scalar CSR, paired edge halves) ----
  aggregate_kernel<<<8 * AGG_BPS, 256, 0, stream>>>((const uint32*)buf1, csr, rowstart, disq, b_conv + 2 * DFEAT, (uint32*)buf0, st2);
  xform_w_kernel<<<DFEAT, 128, 0, stream>>>(w_post1, b_post1, st2, bng_g + 4 * DFEAT, bng_b + 4 * DFEAT, invN, BT, biasx, DFEAT, DFEAT);

  // ---- GEMM4: R4 = relu(BN4(RC) @ Wp1 + bp1), stats->BN5 ----
  gemm_bf16<true, true, false><<<ggrid, 256, 0, stream>>>(buf0, DFEAT, BT, DFEAT, biasx, nullptr, buf1, DFEAT, DFEAT, st3);
  xform_w_kernel<<<DFEAT, 128, 0, stream>>>(w_post2, b_post2, st3, bng_g + 5 * DFEAT, bng_b + 5 * DFEAT, invN, BT, biasx, DFEAT, DFEAT);

  // ---- GEMM5: R5 = relu(BN5(R4) @ Wp2 + bp2), stats->BN6 ----
  gemm_bf16<true, true, false><<<ggrid, 256, 0, stream>>>(buf1, DFEAT, BT, DFEAT, biasx, nullptr, buf0, DFEAT, DFEAT, st4);

  // ---- fused gather+cat, BN affines, output ----
  catgather_kernel<<<dim3(6, 8), 1024, 0, stream>>>(mask, buf0, st4, bng_g + 6 * DFEAT, bng_b + 6 * DFEAT, invN, w_cat, b_cat, catrelu);
  bnstats_kernel<<<12, 64, 0, stream>>>(catrelu, Hpart, Hsent, bn_g, bn_b, aff64);
  final_kernel<<<64, 256, 0, stream>>>(Hsent, catrelu, aff64, w_out, b_out, out);
}